// Round 19
// baseline (210.136 us; speedup 1.0000x reference)
//
#include <hip/hip_runtime.h>

typedef __attribute__((ext_vector_type(4))) float f32x4;
typedef __attribute__((ext_vector_type(8))) short s16x8;
typedef __attribute__((ext_vector_type(4))) short s16x4;
typedef __attribute__((ext_vector_type(2))) unsigned int u32x2;
typedef unsigned short u16;

#define T_SEQ 2048
#define EMB   2048
#define NHEAD 16
#define G32   32
#define DH    64
#define DV    128
#define NEGV  (-1e9f)
// LAMBDA_INIT = 0.8 - 0.6*exp(-0.3*12)
#define LAMBDA_INIT 0.7836057665316245f
#define SCALING 0.125f

__device__ __forceinline__ u16 f2bf(float f) {
    unsigned int u = __builtin_bit_cast(unsigned int, f);
    unsigned int r = (u + 0x7fffu + ((u >> 16) & 1u)) >> 16;
    return (u16)r;
}
__device__ __forceinline__ float bf2f(unsigned int u) {
    return __builtin_bit_cast(float, u << 16);
}
__device__ __forceinline__ unsigned int cvt_pk_bf16(float lo, float hi) {
    unsigned int r;
    asm("v_cvt_pk_bf16_f32 %0, %1, %2" : "=v"(r) : "v"(lo), "v"(hi));
    return r;
}
__device__ __forceinline__ void load16(const u16* g, u16* l) {
    __builtin_amdgcn_global_load_lds(
        (const __attribute__((address_space(1))) unsigned int*)g,
        (__attribute__((address_space(3))) unsigned int*)l, 16, 0, 0);
}

#define BARX asm volatile("s_barrier" ::: "memory")
#define VMW(n) asm volatile("s_waitcnt vmcnt(" #n ")" ::: "memory")

// ---------------- lambda scalar ----------------
__global__ void k_lambda(const float* lq1, const float* lk1,
                         const float* lq2, const float* lk2, float* lam) {
    int l = threadIdx.x;  // 64
    float a = lq1[l] * lk1[l];
    float b = lq2[l] * lk2[l];
    for (int m = 32; m; m >>= 1) { a += __shfl_xor(a, m); b += __shfl_xor(b, m); }
    if (l == 0) *lam = __expf(a) - __expf(b) + LAMBDA_INIT;
}

// ---------------- rope tables (2048 x 32) ----------------
__global__ void k_ropetab(float* cost, float* sint) {
    int i = blockIdx.x * 256 + threadIdx.x;  // 65536
    int j = i & 31, t = i >> 5;
    double invf = exp(-(double)j * (9.210340371976184 / 32.0));  // 10000^(-j/32)
    double fr = (double)t * invf;
    cost[i] = (float)cos(fr);
    sint[i] = (float)sin(fr);
}

// ---------------- x fp32 -> bf16 ----------------
__global__ void k_cvt_x(const float* __restrict__ in, u16* __restrict__ out) {
    int i = blockIdx.x * 256 + threadIdx.x;  // one per 4 elems
    f32x4 v = *(const f32x4*)(in + (size_t)i * 4);
    s16x4 o;
    for (int j = 0; j < 4; j++) o[j] = (short)f2bf(v[j]);
    *(s16x4*)(out + (size_t)i * 4) = o;
}

// ---------------- 4x 2048x2048 fp32 -> transposed bf16 (one dispatch) -------
__global__ __launch_bounds__(256)
void k_transpose_cvt(const float* __restrict__ s0, const float* __restrict__ s1,
                     const float* __restrict__ s2, const float* __restrict__ s3,
                     u16* __restrict__ dqkv, u16* __restrict__ dwo) {
    __shared__ float tile[32][33];
    int z = blockIdx.z;
    const float* in = (z == 0) ? s0 : (z == 1) ? s1 : (z == 2) ? s2 : s3;
    u16* out = (z < 3) ? dqkv + (size_t)z * EMB * EMB : dwo;
    int lc = threadIdx.x & 31;
    int lr0 = (threadIdx.x >> 5) * 4;
    int col = blockIdx.x * 32 + lc;
    int row0 = blockIdx.y * 32 + lr0;
    for (int r = 0; r < 4; r++)
        tile[lr0 + r][lc] = in[(size_t)(row0 + r) * 2048 + col];
    __syncthreads();
    int ncol = blockIdx.y * 32 + lc;
    int nrow0 = blockIdx.x * 32 + lr0;
    for (int r = 0; r < 4; r++)
        out[(size_t)(nrow0 + r) * 2048 + ncol] = f2bf(tile[lc][lr0 + r]);
}

// ---------------- 2048x2048 bf16 -> transposed bf16 (V) ----------------------
__global__ __launch_bounds__(256)
void k_transpose_bf(const u16* __restrict__ in, u16* __restrict__ out) {
    __shared__ u16 tl[64][72];
    int tid = threadIdx.x;
    int lr = tid >> 3;            // 0..31
    int lc8 = (tid & 7) * 8;      // 0..56
    int row0 = blockIdx.y * 64, col0 = blockIdx.x * 64;
    for (int p = 0; p < 2; p++) {
        int r = lr + p * 32;
        *(s16x8*)&tl[r][lc8] = *(const s16x8*)(in + (size_t)(row0 + r) * 2048 + col0 + lc8);
    }
    __syncthreads();
    for (int p = 0; p < 2; p++) {
        int c = lr + p * 32;      // output row = original col
        s16x8 v;
        for (int j = 0; j < 8; j++) v[j] = tl[lc8 + j][c];
        *(s16x8*)(out + (size_t)(col0 + c) * 2048 + row0 + lc8) = v;
    }
}

// ---------------- pipelined 64x256 GEMM, fused QKV epilogue ------------------
// BM=64, BN=256, 4 waves (1M x 4N, per-wave 64x64), BK=32, LDS 40KB (2 bufs).
// Grid 768 = 32 bm x 24 bn = EXACTLY 3 blocks/CU (was 192 = 0.75/CU).
// Asymmetric stages: A-tile = 1 load16 round, B-tile = 4 rounds.
// VMW derivation (FIFO, in-order completion): steady [1,4,1,4]:
//  P0 end: need B(e) done, younger = A(e+1):1      -> VMW(1)
//  P1 end: need A(e+1) done, younger = B(e+1):4    -> VMW(4)
//  P2 end: need B(e+1) done, younger = A(e+2):1    -> VMW(1) (tail: VMW(0))
//  P3 end: need A(e+2) done, younger = B(e+2):4    -> VMW(4) (tail: none)
// Prologue: A(0):1 + B(0):4 outstanding, need A(0) -> VMW(4).
__global__ __launch_bounds__(256, 3)
void k_gemm8(const u16* __restrict__ A, const u16* __restrict__ Bt,
             u16* __restrict__ Cqk, u16* __restrict__ Cv,
             const float* __restrict__ costab, const float* __restrict__ sintab) {
    __shared__ u16 sm[20480];   // 40 KB: buf{0,1} x [ A 64x32 | B 256x32 ]
    int tid = threadIdx.x;
    int w = tid >> 6, l = tid & 63;
    int rl = l & 15, rg = l >> 4;
    int bm = blockIdx.x & 31, bn = blockIdx.x >> 5;
    int t0 = bm * 64, n0 = bn * 256;
    // fragment read addressing; swizzle key (row>>1)&3 == (rl>>1)&3 (rows = 16k+rl)
    int colA = (rg * 8) ^ (((rl >> 1) & 3) << 3);
    int aBase = rl * 32 + colA;                      // shared by all 4 waves (broadcast)
    int bBase = 2048 + w * 2048 + rl * 32 + colA;    // wave's 64-row B group
    // stage addressing: dest linear; source col pre-swizzled (key (srow>>1)&3 = (tid>>3)&3)
    int srow = tid >> 2;                               // 0..63
    int cxor = (((tid & 3) ^ ((tid >> 3) & 3)) << 3);  // source col elems
    int dstoff = tid * 8;                              // elems
    const u16* Ag = A + (size_t)t0 * 2048 + cxor;
    const u16* Bg = Bt + (size_t)n0 * 2048 + cxor;

#define RD_A(arr, co) { _Pragma("unroll") for (int m_ = 0; m_ < 4; m_++) \
    arr[m_] = *(const s16x8*)&sm[(co) + aBase + m_ * 512]; }
#define RD_B(arr, co) { _Pragma("unroll") for (int n_ = 0; n_ < 4; n_++) \
    arr[n_] = *(const s16x8*)&sm[(co) + bBase + n_ * 512]; }
#define MMG(aa, bb, nlo) { __builtin_amdgcn_s_setprio(1); \
    _Pragma("unroll") for (int q_ = 0; q_ < 4; q_++) { \
      acc[q_][nlo]     = __builtin_amdgcn_mfma_f32_16x16x32_bf16(aa[q_], bb[nlo],     acc[q_][nlo],     0, 0, 0); \
      acc[q_][nlo + 1] = __builtin_amdgcn_mfma_f32_16x16x32_bf16(aa[q_], bb[nlo + 1], acc[q_][nlo + 1], 0, 0, 0); } \
    __builtin_amdgcn_s_setprio(0); }
#define STAGE_A(tile) { int nb_ = ((tile) & 1) * 10240; \
    const u16* s_ = Ag + (size_t)srow * 2048 + (tile) * 32; \
    load16(s_, sm + nb_ + dstoff); }
#define STAGE_B(tile) { int nb_ = ((tile) & 1) * 10240 + 2048; \
    const u16* s_ = Bg + (size_t)srow * 2048 + (tile) * 32; \
    load16(s_, sm + nb_ + dstoff); \
    load16(s_ + (size_t)64 * 2048,  sm + nb_ + 2048 + dstoff); \
    load16(s_ + (size_t)128 * 2048, sm + nb_ + 4096 + dstoff); \
    load16(s_ + (size_t)192 * 2048, sm + nb_ + 6144 + dstoff); }

    f32x4 acc[4][4] = {};
    s16x8 aA[4], aB[4], bA[4], bB[4];
    STAGE_A(0); STAGE_B(0);
    VMW(4); BARX;
    for (int i = 0; i < 32; i++) {
        int e = 2 * i;
        bool s2 = i < 31;
        // P0: read A(e), stage A(e+1), mfma tile e-1 {n0,n1}
        RD_A(aA, 0);
        STAGE_A(e + 1);
        BARX;
        if (i) MMG(aB, bB, 0);
        VMW(1); BARX;
        // P1: read B(e), stage B(e+1), mfma tile e-1 {n2,n3}
        RD_B(bA, 0);
        STAGE_B(e + 1);
        BARX;
        if (i) MMG(aB, bB, 2);
        VMW(4); BARX;
        // P2: read A(e+1), stage A(e+2), mfma tile e {n0,n1}
        RD_A(aB, 10240);
        if (s2) STAGE_A(e + 2);
        BARX;
        MMG(aA, bA, 0);
        if (s2) { VMW(1); } else { VMW(0); }
        BARX;
        // P3: read B(e+1), stage B(e+2), mfma tile e {n2,n3}
        RD_B(bB, 10240);
        if (s2) STAGE_B(e + 2);
        BARX;
        MMG(aA, bA, 2);
        if (s2) VMW(4);
        BARX;
    }
    // drain: tile 63's MFMA
    MMG(aB, bB, 0);
    MMG(aB, bB, 2);
#undef RD_A
#undef RD_B
#undef MMG
#undef STAGE_A
#undef STAGE_B
    // epilogue: rope for Q/K cols, plain bf16 (t,e) for V cols
    int nbase = n0 + w * 64;           // wave's 64 cols = one sub-head
    if (nbase >= 4096) {
        int col = nbase - 4096;
        for (int m = 0; m < 4; m++) {
            int trow = t0 + m * 16 + rg * 4;
            for (int n = 0; n < 4; n++)
                for (int r = 0; r < 4; r++)
                    Cv[(size_t)(trow + r) * 2048 + col + n * 16 + rl] = f2bf(acc[m][n][r]);
        }
    } else {
        const bool isQ = nbase < 2048;
        u16* dst = isQ ? Cqk : Cqk + (size_t)G32 * 2048 * 64;
        int g = (isQ ? nbase : nbase - 2048) >> 6;
        float fs = isQ ? SCALING : 1.0f;
        for (int m = 0; m < 4; m++) {
            int trow = t0 + m * 16 + rg * 4;
            for (int n = 0; n < 4; n++) {
                int d = n * 16 + rl;           // 0..63
                int np = n ^ 2;                // paired fragment (d +/- 32)
                float sgn = (n < 2) ? -1.f : 1.f;
                for (int r = 0; r < 4; r++) {
                    int t = trow + r;
                    float c = costab[t * 32 + (d & 31)];
                    float s = sintab[t * 32 + (d & 31)];
                    float v = (acc[m][n][r] * c + sgn * acc[m][np][r] * s) * fs;
                    dst[((size_t)g * 2048 + t) * 64 + d] = f2bf(v);
                }
            }
        }
    }
}

// ---------------- pipelined 128x128 GEMM, split-K=2 fp32 partials (out-proj) -
// (unchanged from R18, which passed)
__global__ __launch_bounds__(256, 2)
void k_gemm0(const u16* __restrict__ A, const u16* __restrict__ Bt,
             float* __restrict__ Cf) {
    __shared__ u16 sm[16384];   // 32 KB: buf{0,1} x { A 128x32 | B 128x32 }
    int tid = threadIdx.x;
    int w = tid >> 6, l = tid & 63;
    int wm = w >> 1, wn = w & 1;
    int rl = l & 15, rg = l >> 4;
    int t0 = blockIdx.y * 128, n0 = blockIdx.x * 128;
    int kbase = blockIdx.z * 1024;     // 32 K-tiles of 32
    Cf += (size_t)blockIdx.z * 2048 * 2048;
    int colA = (rg * 8) ^ (((rl >> 1) & 3) << 3);
    int aBase = wm * 2048 + rl * 32 + colA;
    int bBase = 4096 + wn * 2048 + rl * 32 + colA;
    int srow = tid >> 2;                               // 0..63
    int cxor = (((tid & 3) ^ ((tid >> 3) & 3)) << 3);  // source col pre-swizzle
    int dstoff = tid * 8;                              // elems
    const u16* Ag = A + (size_t)t0 * 2048 + kbase + cxor;
    const u16* Bg = Bt + (size_t)n0 * 2048 + kbase + cxor;

#define RD_A(arr, co) { _Pragma("unroll") for (int m_ = 0; m_ < 4; m_++) \
    arr[m_] = *(const s16x8*)&sm[(co) + aBase + m_ * 512]; }
#define RD_B(arr, co) { _Pragma("unroll") for (int n_ = 0; n_ < 4; n_++) \
    arr[n_] = *(const s16x8*)&sm[(co) + bBase + n_ * 512]; }
#define MMG(aa, bb, nlo) { __builtin_amdgcn_s_setprio(1); \
    _Pragma("unroll") for (int q_ = 0; q_ < 4; q_++) { \
      acc[q_][nlo]     = __builtin_amdgcn_mfma_f32_16x16x32_bf16(aa[q_], bb[nlo],     acc[q_][nlo],     0, 0, 0); \
      acc[q_][nlo + 1] = __builtin_amdgcn_mfma_f32_16x16x32_bf16(aa[q_], bb[nlo + 1], acc[q_][nlo + 1], 0, 0, 0); } \
    __builtin_amdgcn_s_setprio(0); }
#define STAGE_A(tile) { int nb_ = ((tile) & 1) * 8192; \
    const u16* s_ = Ag + (size_t)srow * 2048 + (tile) * 32; \
    load16(s_, sm + nb_ + dstoff); \
    load16(s_ + (size_t)64 * 2048, sm + nb_ + 2048 + dstoff); }
#define STAGE_B(tile) { int nb_ = ((tile) & 1) * 8192 + 4096; \
    const u16* s_ = Bg + (size_t)srow * 2048 + (tile) * 32; \
    load16(s_, sm + nb_ + dstoff); \
    load16(s_ + (size_t)64 * 2048, sm + nb_ + 2048 + dstoff); }

    f32x4 acc[4][4] = {};
    s16x8 aA[4], aB[4], bA[4], bB[4];
    STAGE_A(0); STAGE_B(0);
    VMW(2); BARX;
    for (int i = 0; i < 16; i++) {
        int e = 2 * i;
        bool s2 = i < 15;
        RD_A(aA, 0);
        STAGE_A(e + 1);
        BARX;
        if (i) MMG(aB, bB, 0);
        VMW(2); BARX;
        RD_B(bA, 0);
        STAGE_B(e + 1);
        BARX;
        if (i) MMG(aB, bB, 2);
        VMW(2); BARX;
        RD_A(aB, 8192);
        if (s2) STAGE_A(e + 2);
        BARX;
        MMG(aA, bA, 0);
        if (s2) { VMW(2); } else { VMW(0); }
        BARX;
        RD_B(bB, 8192);
        if (s2) STAGE_B(e + 2);
        BARX;
        MMG(aA, bA, 2);
        if (s2) VMW(2);
        BARX;
    }
    MMG(aB, bB, 0);
    MMG(aB, bB, 2);
#undef RD_A
#undef RD_B
#undef MMG
#undef STAGE_A
#undef STAGE_B
    for (int i = 0; i < 4; i++) {
        int trow = t0 + wm * 64 + i * 16 + rg * 4;
        for (int j = 0; j < 4; j++) {
            int col = n0 + wn * 64 + j * 16 + rl;
            for (int r = 0; r < 4; r++)
                Cf[(size_t)(trow + r) * 2048 + col] = acc[i][j][r];
        }
    }
}

// ---------------- out-proj partial add ----------------
__global__ void k_oadd(const float* __restrict__ p, float* __restrict__ out) {
    int i = blockIdx.x * 256 + threadIdx.x;
    f32x4 a = *(const f32x4*)(p + (size_t)i * 4);
    f32x4 b = *(const f32x4*)(p + (size_t)4194304 + i * 4);
    for (int j = 0; j < 4; j++) a[j] += b[j];
    *(f32x4*)(out + (size_t)i * 4) = a;
}

// ---------------- differential flash attention (swapped-QK, 2 q-tiles/wave) -
// Balanced CU pairing: blocks b and b+256 co-reside; qs mapping makes every
// pair sum to 34 block-iters, and they share g=b&31 (K/V in L2).
// 1 barrier/tile; 2 q-tiles/wave. (unchanged from R18, which passed)
__global__ __launch_bounds__(256, 2)
void k_flash(const u16* __restrict__ qb_, const u16* __restrict__ kb,
             const u16* __restrict__ vt, u16* __restrict__ Ob) {
    __shared__ u16 Vt[2][128 * 64];
    __shared__ u16 Pb[4][32 * 64];
    int b = blockIdx.x;
    int qs = (b < 256) ? (15 - (b >> 5)) : ((b - 256) >> 5);
    int g = b & 31;               // same-g blocks share XCD (stride 32 ≡ 0 mod 8)
    int h = g >> 1;
    int tid = threadIdx.x, lane = tid & 63, wid = tid >> 6;
    int q0w = qs * 128 + wid * 32;    // wave owns q rows [q0w, q0w+32)
    int rl = lane & 15, rg = lane >> 4;
    int rl7s = (rl & 7) << 4;     // bank swizzle
    // Q fragments (operand B of swapped QK), 2 q-halves
    s16x8 aQ[2][2];
    for (int mf = 0; mf < 2; mf++) {
        const u16* qbase = qb_ + ((size_t)(g * 2048 + q0w + mf * 16 + rl)) * 64 + rg * 8;
        aQ[mf][0] = *(const s16x8*)qbase;
        aQ[mf][1] = *(const s16x8*)(qbase + 32);
    }
    // staging / fragment address bases
    int srow = tid >> 3;          // 0..31
    int scol = (tid & 7) * 8;     // 0..56
    const u16* vbase = vt + ((size_t)(h * 128 + srow)) * 2048 + scol;
    const u16* kbase = kb + ((size_t)(g * 2048 + rl)) * 64 + rg * 8;
    // prologue: tile 0 into regs
    s16x8 vv[4], bK[4][2];
    for (int p = 0; p < 4; p++) vv[p] = *(const s16x8*)(vbase + (size_t)p * 32 * 2048);
    for (int nf = 0; nf < 4; nf++)
        for (int ks = 0; ks < 2; ks++)
            bK[nf][ks] = *(const s16x8*)(kbase + (size_t)nf * 16 * 64 + ks * 32);
    f32x4 Oa[2][8] = {};
    float mrow[2] = {-3e38f, -3e38f}, lrow[2] = {0.f, 0.f};
    char* pbw = (char*)&Pb[wid][0];
    int ntiles = 2 * qs + 2;
    for (int it = 0; it < ntiles; it++) {
        int kv0 = it * 64;
        char* Vb = (char*)&Vt[it & 1][0];
        // write staged V (swizzled) — block-cooperative, unconditional
        for (int p = 0; p < 4; p++) {
            int row = srow + p * 32;
            *(s16x8*)(Vb + ((row * 128 + scol * 2) ^ ((row & 7) << 4))) = vv[p];
        }
        bool more = (it + 1 < ntiles);
        if (more)
            for (int p = 0; p < 4; p++)
                vv[p] = *(const s16x8*)(vbase + (size_t)p * 32 * 2048 + kv0 + 64);
        __syncthreads();
        bool active = (kv0 <= q0w + 31);           // wave-uniform
        bool nextact = more && (kv0 + 64 <= q0w + 31);
        if (active) {
            // S^T = K.Q^T : St[mf][nf][r] = S[kv0+nf*16+rg*4+r][q0w+mf*16+rl]
            f32x4 St[2][4];
            for (int mf = 0; mf < 2; mf++)
                for (int nf = 0; nf < 4; nf++) {
                    f32x4 s = {};
                    s = __builtin_amdgcn_mfma_f32_16x16x32_bf16(bK[nf][0], aQ[mf][0], s, 0, 0, 0);
                    s = __builtin_amdgcn_mfma_f32_16x16x32_bf16(bK[nf][1], aQ[mf][1], s, 0, 0, 0);
                    St[mf][nf] = s;
                }
            if (nextact)
                for (int nf = 0; nf < 4; nf++)
                    for (int ks = 0; ks < 2; ks++)
                        bK[nf][ks] = *(const s16x8*)(kbase + (size_t)(kv0 + 64 + nf * 16) * 64 + ks * 32);
            if (kv0 + 63 > q0w) {     // diagonal region: per-element mask
                for (int mf = 0; mf < 2; mf++) {
                    int q = q0w + mf * 16 + rl;
                    for (int nf = 0; nf < 4; nf++)
                        for (int r = 0; r < 4; r++)
                            if (kv0 + nf * 16 + rg * 4 + r > q) St[mf][nf][r] = NEGV;
                }
            }
            // two independent softmax chains (ILP)
            float pmax[2];
            for (int mf = 0; mf < 2; mf++) {
                float m0 = fmaxf(fmaxf(St[mf][0][0], St[mf][0][1]), fmaxf(St[mf][0][2], St[mf][0][3]));
                float m1 = fmaxf(fmaxf(St[mf][1][0], St[mf][1][1]), fmaxf(St[mf][1][2], St[mf][1][3]));
                float m2 = fmaxf(fmaxf(St[mf][2][0], St[mf][2][1]), fmaxf(St[mf][2][2], St[mf][2][3]));
                float m3 = fmaxf(fmaxf(St[mf][3][0], St[mf][3][1]), fmaxf(St[mf][3][2], St[mf][3][3]));
                float px = fmaxf(fmaxf(m0, m1), fmaxf(m2, m3));
                px = fmaxf(px, __shfl_xor(px, 16));
                px = fmaxf(px, __shfl_xor(px, 32));
                pmax[mf] = px;
            }
            // defer-max (T13) per half
            for (int mf = 0; mf < 2; mf++) {
                if (__any(pmax[mf] > mrow[mf] + 8.f)) {
                    float nm = fmaxf(mrow[mf], pmax[mf]);
                    float sc = __expf(mrow[mf] - nm);
                    mrow[mf] = nm;
                    lrow[mf] *= sc;
                    int sci = __builtin_bit_cast(int, sc);
                    for (int r = 0; r < 4; r++) {
                        float sr = __builtin_bit_cast(float,
                            __builtin_amdgcn_ds_bpermute((rg * 20 + r) * 4, sci));
                        for (int nf = 0; nf < 8; nf++) Oa[mf][nf][r] *= sr;
                    }
                }
            }
            // P = exp(S - mrow); row sums
            for (int mf = 0; mf < 2; mf++) {
                for (int nf = 0; nf < 4; nf++)
                    for (int r = 0; r < 4; r++)
                        St[mf][nf][r] = __expf(St[mf][nf][r] - mrow[mf]);
                float s0 = (St[mf][0][0] + St[mf][0][1]) + (St[mf][0][2] + St[mf][0][3]);
                float s1 = (St[mf][1][0] + St[mf][1][1]) + (St[mf][1][2] + St[mf][1][3]);
                float s2 = (St[mf][2][0] + St[mf][2][1]) + (St[mf][2][2] + St[mf][2][3]);
                float s3 = (St[mf][3][0] + St[mf][3][1]) + (St[mf][3][2] + St[mf][3][3]);
                float rs = (s0 + s1) + (s2 + s3);
                rs += __shfl_xor(rs, 16);
                rs += __shfl_xor(rs, 32);
                lrow[mf] += rs;
            }
            // pack P^T -> row-q LDS (per-wave, swizzled); rows mf*16+rl
            for (int mf = 0; mf < 2; mf++) {
                char* pm = pbw + (mf * 16 + rl) * 128;
                for (int nf = 0; nf < 4; nf++) {
                    unsigned int w0 = cvt_pk_bf16(St[mf][nf][0], St[mf][nf][1]);
                    unsigned int w1 = cvt_pk_bf16(St[mf][nf][2], St[mf][nf][3]);
                    u32x2 wp = {w0, w1};
                    *(u32x2*)(pm + ((nf * 32 + rg * 8) ^ rl7s)) = wp;
                }
            }
            s16x8 aP[2][2];
            for (int mf = 0; mf < 2; mf++) {
                char* pm = pbw + (mf * 16 + rl) * 128;
                for (int ks = 0; ks < 2; ks++)
                    aP[mf][ks] = *(const s16x8*)(pm + ((ks * 64 + rg * 16) ^ rl7s));
            }
            // PV: each bV read shared by both q-halves
            for (int ks = 0; ks < 2; ks++)
                for (int nf = 0; nf < 8; nf++) {
                    int row = nf * 16 + rl;
                    s16x8 bV = *(const s16x8*)(Vb + ((row * 128 + ks * 64 + rg * 16) ^ ((row & 7) << 4)));
                    Oa[0][nf] = __builtin_amdgcn_mfma_f32_16x16x32_bf16(aP[0][ks], bV, Oa[0][nf], 0, 0, 0);
                    Oa[1][nf] = __builtin_amdgcn_mfma_f32_16x16x32_bf16(aP[1][ks], bV, Oa[1][nf], 0, 0, 0);
                }
        }
        // no trailing barrier: next iter's mid-barrier orders reuse of Vt[it&1]
    }
    // epilogue: broadcast 1/l per half, write bf16
    for (int mf = 0; mf < 2; mf++) {
        float inv = 1.f / lrow[mf];
        int invi = __builtin_bit_cast(int, inv);
        for (int r = 0; r < 4; r++) {
            float ir = __builtin_bit_cast(float,
                __builtin_amdgcn_ds_bpermute((rg * 20 + r) * 4, invi));
            int t = q0w + mf * 16 + rg * 4 + r;
            for (int nf = 0; nf < 8; nf++)
                Ob[((size_t)(g * 2048 + t)) * 128 + nf * 16 + rl] = f2bf(Oa[mf][nf][r] * ir);
        }
    }
}

// ---------------- combine O0 - lam*O1, RMSNorm, -> bf16 (t, e) ----------------
__global__ __launch_bounds__(256)
void k_combine(const u16* __restrict__ O, const float* __restrict__ lamp,
               const float* __restrict__ subw, u16* __restrict__ Ab) {
    int gw = blockIdx.x * 4 + (threadIdx.x >> 6);  // 0..32767
    int lane = threadIdx.x & 63;
    int h = gw >> 11;
    int t = gw & 2047;
    float lam = *lamp;
    const u16* o0 = O + ((size_t)((2 * h) * 2048 + t)) * 128 + lane * 2;
    const u16* o1 = O + ((size_t)((2 * h + 1) * 2048 + t)) * 128 + lane * 2;
    unsigned int p0 = *(const unsigned int*)o0;
    unsigned int p1 = *(const unsigned int*)o1;
    float a0 = bf2f(p0 & 0xffffu) - lam * bf2f(p1 & 0xffffu);
    float a1 = bf2f(p0 >> 16) - lam * bf2f(p1 >> 16);
    float ss = a0 * a0 + a1 * a1;
    for (int m = 1; m < 64; m <<= 1) ss += __shfl_xor(ss, m);
    float inv = rsqrtf(ss * (1.f / 128.f) + 1e-5f) * (1.f - LAMBDA_INIT);
    a0 *= inv * subw[lane * 2];
    a1 *= inv * subw[lane * 2 + 1];
    unsigned int pk = (unsigned int)f2bf(a0) | ((unsigned int)f2bf(a1) << 16);
    *(unsigned int*)(Ab + (size_t)t * 2048 + h * 128 + lane * 2) = pk;
}

extern "C" void kernel_launch(void* const* d_in, const int* in_sizes, int n_in,
                              void* d_out, int out_size, void* d_ws, size_t ws_size,
                              hipStream_t stream) {
    const float* x    = (const float*)d_in[0];
    const float* Wq   = (const float*)d_in[2];
    const float* Wk   = (const float*)d_in[3];
    const float* Wv   = (const float*)d_in[4];
    const float* Wo   = (const float*)d_in[5];
    const float* lq1  = (const float*)d_in[6];
    const float* lk1  = (const float*)d_in[7];
    const float* lq2  = (const float*)d_in[8];
    const float* lk2  = (const float*)d_in[9];
    const float* subw = (const float*)d_in[10];
    float* out = (float*)d_out;

    char* ws = (char*)d_ws;
    size_t off = 0;
    auto alloc = [&](size_t sz) -> char* {
        char* p = ws + off;
        off = (off + sz + 255) & ~(size_t)255;
        return p;
    };
    float* lam  = (float*)alloc(4);
    float* cost = (float*)alloc((size_t)T_SEQ * 32 * 4);
    float* sint = (float*)alloc((size_t)T_SEQ * 32 * 4);
    u16* xbf   = (u16*)alloc((size_t)T_SEQ * EMB * 2);
    u16* wqkvt = (u16*)alloc((size_t)3 * EMB * EMB * 2);   // [WqT;WkT;WvT] 6144x2048
    u16* wot   = (u16*)alloc((size_t)EMB * EMB * 2);
    u16* qkbuf = (u16*)alloc((size_t)2 * G32 * T_SEQ * DH * 2);  // qbf | kbf
    u16* vtb   = (u16*)alloc((size_t)NHEAD * DV * T_SEQ * 2);
    u16* Obuf  = (u16*)alloc((size_t)G32 * T_SEQ * DV * 2);
    u16* Abf   = (u16*)alloc((size_t)T_SEQ * EMB * 2);
    float* parts = (float*)alloc((size_t)2 * EMB * EMB * 4);     // split-K partials
    u16* qbf = qkbuf;
    u16* kbf = qkbuf + (size_t)G32 * T_SEQ * DH;
    u16* vbf = (u16*)parts;  // alias: V (t,e) bf16, consumed before out-proj partials

    k_lambda<<<1, 64, 0, stream>>>(lq1, lk1, lq2, lk2, lam);
    k_ropetab<<<256, 256, 0, stream>>>(cost, sint);
    k_cvt_x<<<4096, 256, 0, stream>>>(x, xbf);
    k_transpose_cvt<<<dim3(64, 64, 4), 256, 0, stream>>>(Wq, Wk, Wv, Wo, wqkvt, wot);
    // fused Q|K|V projection (N=6144), pipelined 64x256 kernel, 768 blocks = 3/CU
    k_gemm8<<<768, 256, 0, stream>>>(xbf, wqkvt, qkbuf, vbf, cost, sint);
    k_transpose_bf<<<dim3(32, 32), 256, 0, stream>>>(vbf, vtb);
    k_flash<<<512, 256, 0, stream>>>(qbf, kbf, vtb, Obuf);
    k_combine<<<8192, 256, 0, stream>>>(Obuf, lam, subw, Abf);
    // out projection, split-K=2, pipelined 128x128 kernel
    k_gemm0<<<dim3(16, 16, 2), 256, 0, stream>>>(Abf, wot, parts);
    k_oadd<<<4096, 256, 0, stream>>>(parts, out);
}

// Round 20
// 190.051 us; speedup vs baseline: 1.1057x; 1.1057x over previous
//
#include <hip/hip_runtime.h>

typedef __attribute__((ext_vector_type(4))) float f32x4;
typedef __attribute__((ext_vector_type(8))) short s16x8;
typedef __attribute__((ext_vector_type(4))) short s16x4;
typedef __attribute__((ext_vector_type(2))) unsigned int u32x2;
typedef unsigned short u16;

#define T_SEQ 2048
#define EMB   2048
#define NHEAD 16
#define G32   32
#define DH    64
#define DV    128
#define NEGV  (-1e9f)
// LAMBDA_INIT = 0.8 - 0.6*exp(-0.3*12)
#define LAMBDA_INIT 0.7836057665316245f
#define SCALING 0.125f

__device__ __forceinline__ u16 f2bf(float f) {
    unsigned int u = __builtin_bit_cast(unsigned int, f);
    unsigned int r = (u + 0x7fffu + ((u >> 16) & 1u)) >> 16;
    return (u16)r;
}
__device__ __forceinline__ float bf2f(unsigned int u) {
    return __builtin_bit_cast(float, u << 16);
}
__device__ __forceinline__ unsigned int cvt_pk_bf16(float lo, float hi) {
    unsigned int r;
    asm("v_cvt_pk_bf16_f32 %0, %1, %2" : "=v"(r) : "v"(lo), "v"(hi));
    return r;
}
__device__ __forceinline__ void load16(const u16* g, u16* l) {
    __builtin_amdgcn_global_load_lds(
        (const __attribute__((address_space(1))) unsigned int*)g,
        (__attribute__((address_space(3))) unsigned int*)l, 16, 0, 0);
}

#define BARX asm volatile("s_barrier" ::: "memory")
#define VMW(n) asm volatile("s_waitcnt vmcnt(" #n ")" ::: "memory")

// ---------------- lambda scalar ----------------
__global__ void k_lambda(const float* lq1, const float* lk1,
                         const float* lq2, const float* lk2, float* lam) {
    int l = threadIdx.x;  // 64
    float a = lq1[l] * lk1[l];
    float b = lq2[l] * lk2[l];
    for (int m = 32; m; m >>= 1) { a += __shfl_xor(a, m); b += __shfl_xor(b, m); }
    if (l == 0) *lam = __expf(a) - __expf(b) + LAMBDA_INIT;
}

// ---------------- rope tables (2048 x 32) ----------------
__global__ void k_ropetab(float* cost, float* sint) {
    int i = blockIdx.x * 256 + threadIdx.x;  // 65536
    int j = i & 31, t = i >> 5;
    double invf = exp(-(double)j * (9.210340371976184 / 32.0));  // 10000^(-j/32)
    double fr = (double)t * invf;
    cost[i] = (float)cos(fr);
    sint[i] = (float)sin(fr);
}

// ---------------- x fp32 -> bf16 ----------------
__global__ void k_cvt_x(const float* __restrict__ in, u16* __restrict__ out) {
    int i = blockIdx.x * 256 + threadIdx.x;  // one per 4 elems
    f32x4 v = *(const f32x4*)(in + (size_t)i * 4);
    s16x4 o;
    for (int j = 0; j < 4; j++) o[j] = (short)f2bf(v[j]);
    *(s16x4*)(out + (size_t)i * 4) = o;
}

// ---------------- 4x 2048x2048 fp32 -> transposed bf16 (one dispatch) -------
__global__ __launch_bounds__(256)
void k_transpose_cvt(const float* __restrict__ s0, const float* __restrict__ s1,
                     const float* __restrict__ s2, const float* __restrict__ s3,
                     u16* __restrict__ dqkv, u16* __restrict__ dwo) {
    __shared__ float tile[32][33];
    int z = blockIdx.z;
    const float* in = (z == 0) ? s0 : (z == 1) ? s1 : (z == 2) ? s2 : s3;
    u16* out = (z < 3) ? dqkv + (size_t)z * EMB * EMB : dwo;
    int lc = threadIdx.x & 31;
    int lr0 = (threadIdx.x >> 5) * 4;
    int col = blockIdx.x * 32 + lc;
    int row0 = blockIdx.y * 32 + lr0;
    for (int r = 0; r < 4; r++)
        tile[lr0 + r][lc] = in[(size_t)(row0 + r) * 2048 + col];
    __syncthreads();
    int ncol = blockIdx.y * 32 + lc;
    int nrow0 = blockIdx.x * 32 + lr0;
    for (int r = 0; r < 4; r++)
        out[(size_t)(nrow0 + r) * 2048 + ncol] = f2bf(tile[lc][lr0 + r]);
}

// ---------------- 2048x2048 bf16 -> transposed bf16 (V) ----------------------
__global__ __launch_bounds__(256)
void k_transpose_bf(const u16* __restrict__ in, u16* __restrict__ out) {
    __shared__ u16 tl[64][72];
    int tid = threadIdx.x;
    int lr = tid >> 3;            // 0..31
    int lc8 = (tid & 7) * 8;      // 0..56
    int row0 = blockIdx.y * 64, col0 = blockIdx.x * 64;
    for (int p = 0; p < 2; p++) {
        int r = lr + p * 32;
        *(s16x8*)&tl[r][lc8] = *(const s16x8*)(in + (size_t)(row0 + r) * 2048 + col0 + lc8);
    }
    __syncthreads();
    for (int p = 0; p < 2; p++) {
        int c = lr + p * 32;      // output row = original col
        s16x8 v;
        for (int j = 0; j < 8; j++) v[j] = tl[lc8 + j][c];
        *(s16x8*)(out + (size_t)(col0 + c) * 2048 + row0 + lc8) = v;
    }
}

// ---------------- pipelined 256x256 GEMM, fused QKV epilogue -----------------
// R18 structure (passed at 65us); ONE change: XCD-patch block remap.
// Old map: XCD (b%8) owned bm=const x ALL 24 bn -> re-reads all of B (25MB/XCD).
// New map: XCD owns a 4bm x 6bn patch -> A 4MB + B 6MB = 10MB/XCD (2.6x less).
// Bijective: bm=(xcd&1)*4+(i&3), bn=(xcd>>1)*6+(i>>2); inverse exists.
__global__ __launch_bounds__(512, 2)
void k_gemm8(const u16* __restrict__ A, const u16* __restrict__ Bt,
             u16* __restrict__ Cqk, u16* __restrict__ Cv,
             const float* __restrict__ costab, const float* __restrict__ sintab) {
    __shared__ u16 sm[32768];   // 64 KB: buf{0,1} x { A 256x32 | B 256x32 }
    int tid = threadIdx.x;
    int w = tid >> 6, l = tid & 63;
    int wm = w >> 2, wn = w & 3;
    int rl = l & 15, rg = l >> 4;
    int xcd = blockIdx.x & 7, ii = blockIdx.x >> 3;
    int bm = (xcd & 1) * 4 + (ii & 3);
    int bn = (xcd >> 1) * 6 + (ii >> 2);
    int t0 = bm * 256, n0 = bn * 256;
    int colA = (rg * 8) ^ (((rl >> 1) & 3) << 3);
    int aBase = wm * 4096 + rl * 32 + colA;
    int bBase = 8192 + (wn >> 1) * 4096 + (wn & 1) * 2048 + rl * 32 + colA;
    int srow = w * 16 + (l >> 2);                     // 0..127 within half
    int cxor = (((l & 3) ^ ((l >> 3) & 3)) << 3);     // source col elems
    int dstoff = w * 512 + l * 8;                     // elems within half
    const u16* Ag = A + (size_t)t0 * 2048 + cxor;
    const u16* Bg = Bt + (size_t)n0 * 2048 + cxor;

#define RD_A(arr, co) { _Pragma("unroll") for (int m_ = 0; m_ < 8; m_++) \
    arr[m_] = *(const s16x8*)&sm[(co) + aBase + m_ * 512]; }
#define RD_B(arr, co) { _Pragma("unroll") for (int n_ = 0; n_ < 4; n_++) \
    arr[n_] = *(const s16x8*)&sm[(co) + bBase + n_ * 512]; }
#define MMG(aa, bb, nlo) { __builtin_amdgcn_s_setprio(1); \
    _Pragma("unroll") for (int q_ = 0; q_ < 8; q_++) { \
      acc[q_][nlo]     = __builtin_amdgcn_mfma_f32_16x16x32_bf16(aa[q_], bb[nlo],     acc[q_][nlo],     0, 0, 0); \
      acc[q_][nlo + 1] = __builtin_amdgcn_mfma_f32_16x16x32_bf16(aa[q_], bb[nlo + 1], acc[q_][nlo + 1], 0, 0, 0); } \
    __builtin_amdgcn_s_setprio(0); }
#define STAGE_A(tile) { int nb_ = ((tile) & 1) * 16384; \
    const u16* s_ = Ag + (size_t)srow * 2048 + (tile) * 32; \
    load16(s_, sm + nb_ + dstoff); \
    load16(s_ + (size_t)128 * 2048, sm + nb_ + 4096 + dstoff); }
#define STAGE_B(tile) { int nb_ = ((tile) & 1) * 16384 + 8192; \
    const u16* s_ = Bg + (size_t)srow * 2048 + (tile) * 32; \
    load16(s_, sm + nb_ + dstoff); \
    load16(s_ + (size_t)128 * 2048, sm + nb_ + 4096 + dstoff); }

    f32x4 acc[8][4] = {};
    s16x8 aA[8], aB[8], bA[4], bB[4];
    STAGE_A(0); STAGE_B(0);
    VMW(2); BARX;
    for (int i = 0; i < 32; i++) {
        int e = 2 * i;
        bool s2 = i < 31;
        RD_A(aA, 0);
        STAGE_A(e + 1);
        BARX;
        if (i) MMG(aB, bB, 0);
        VMW(2); BARX;
        RD_B(bA, 0);
        STAGE_B(e + 1);
        BARX;
        if (i) MMG(aB, bB, 2);
        VMW(2); BARX;
        RD_A(aB, 16384);
        if (s2) STAGE_A(e + 2);
        BARX;
        MMG(aA, bA, 0);
        if (s2) { VMW(2); } else { VMW(0); }
        BARX;
        RD_B(bB, 16384);
        if (s2) STAGE_B(e + 2);
        BARX;
        MMG(aA, bA, 2);
        if (s2) VMW(2);
        BARX;
    }
    MMG(aB, bB, 0);
    MMG(aB, bB, 2);
#undef RD_A
#undef RD_B
#undef MMG
#undef STAGE_A
#undef STAGE_B
    int nbase = n0 + wn * 64;          // wave's 64 cols = one sub-head
    if (nbase >= 4096) {
        int col = nbase - 4096;
        for (int m = 0; m < 8; m++) {
            int trow = t0 + wm * 128 + m * 16 + rg * 4;
            for (int n = 0; n < 4; n++)
                for (int r = 0; r < 4; r++)
                    Cv[(size_t)(trow + r) * 2048 + col + n * 16 + rl] = f2bf(acc[m][n][r]);
        }
    } else {
        const bool isQ = nbase < 2048;
        u16* dst = isQ ? Cqk : Cqk + (size_t)G32 * 2048 * 64;
        int g = (isQ ? nbase : nbase - 2048) >> 6;
        float fs = isQ ? SCALING : 1.0f;
        for (int m = 0; m < 8; m++) {
            int trow = t0 + wm * 128 + m * 16 + rg * 4;
            for (int n = 0; n < 4; n++) {
                int d = n * 16 + rl;           // 0..63
                int np = n ^ 2;                // paired fragment (d +/- 32)
                float sgn = (n < 2) ? -1.f : 1.f;
                for (int r = 0; r < 4; r++) {
                    int t = trow + r;
                    float c = costab[t * 32 + (d & 31)];
                    float s = sintab[t * 32 + (d & 31)];
                    float v = (acc[m][n][r] * c + sgn * acc[m][np][r] * s) * fs;
                    dst[((size_t)g * 2048 + t) * 64 + d] = f2bf(v);
                }
            }
        }
    }
}

// ---------------- pipelined 128x128 GEMM, split-K=2 fp32 partials (out-proj) -
// (unchanged from R18, which passed)
__global__ __launch_bounds__(256, 2)
void k_gemm0(const u16* __restrict__ A, const u16* __restrict__ Bt,
             float* __restrict__ Cf) {
    __shared__ u16 sm[16384];   // 32 KB: buf{0,1} x { A 128x32 | B 128x32 }
    int tid = threadIdx.x;
    int w = tid >> 6, l = tid & 63;
    int wm = w >> 1, wn = w & 1;
    int rl = l & 15, rg = l >> 4;
    int t0 = blockIdx.y * 128, n0 = blockIdx.x * 128;
    int kbase = blockIdx.z * 1024;     // 32 K-tiles of 32
    Cf += (size_t)blockIdx.z * 2048 * 2048;
    int colA = (rg * 8) ^ (((rl >> 1) & 3) << 3);
    int aBase = wm * 2048 + rl * 32 + colA;
    int bBase = 4096 + wn * 2048 + rl * 32 + colA;
    int srow = tid >> 2;                               // 0..63
    int cxor = (((tid & 3) ^ ((tid >> 3) & 3)) << 3);  // source col pre-swizzle
    int dstoff = tid * 8;                              // elems
    const u16* Ag = A + (size_t)t0 * 2048 + kbase + cxor;
    const u16* Bg = Bt + (size_t)n0 * 2048 + kbase + cxor;

#define RD_A(arr, co) { _Pragma("unroll") for (int m_ = 0; m_ < 4; m_++) \
    arr[m_] = *(const s16x8*)&sm[(co) + aBase + m_ * 512]; }
#define RD_B(arr, co) { _Pragma("unroll") for (int n_ = 0; n_ < 4; n_++) \
    arr[n_] = *(const s16x8*)&sm[(co) + bBase + n_ * 512]; }
#define MMG(aa, bb, nlo) { __builtin_amdgcn_s_setprio(1); \
    _Pragma("unroll") for (int q_ = 0; q_ < 4; q_++) { \
      acc[q_][nlo]     = __builtin_amdgcn_mfma_f32_16x16x32_bf16(aa[q_], bb[nlo],     acc[q_][nlo],     0, 0, 0); \
      acc[q_][nlo + 1] = __builtin_amdgcn_mfma_f32_16x16x32_bf16(aa[q_], bb[nlo + 1], acc[q_][nlo + 1], 0, 0, 0); } \
    __builtin_amdgcn_s_setprio(0); }
#define STAGE_A(tile) { int nb_ = ((tile) & 1) * 8192; \
    const u16* s_ = Ag + (size_t)srow * 2048 + (tile) * 32; \
    load16(s_, sm + nb_ + dstoff); \
    load16(s_ + (size_t)64 * 2048, sm + nb_ + 2048 + dstoff); }
#define STAGE_B(tile) { int nb_ = ((tile) & 1) * 8192 + 4096; \
    const u16* s_ = Bg + (size_t)srow * 2048 + (tile) * 32; \
    load16(s_, sm + nb_ + dstoff); \
    load16(s_ + (size_t)64 * 2048, sm + nb_ + 2048 + dstoff); }

    f32x4 acc[4][4] = {};
    s16x8 aA[4], aB[4], bA[4], bB[4];
    STAGE_A(0); STAGE_B(0);
    VMW(2); BARX;
    for (int i = 0; i < 16; i++) {
        int e = 2 * i;
        bool s2 = i < 15;
        RD_A(aA, 0);
        STAGE_A(e + 1);
        BARX;
        if (i) MMG(aB, bB, 0);
        VMW(2); BARX;
        RD_B(bA, 0);
        STAGE_B(e + 1);
        BARX;
        if (i) MMG(aB, bB, 2);
        VMW(2); BARX;
        RD_A(aB, 8192);
        if (s2) STAGE_A(e + 2);
        BARX;
        MMG(aA, bA, 0);
        if (s2) { VMW(2); } else { VMW(0); }
        BARX;
        RD_B(bB, 8192);
        if (s2) STAGE_B(e + 2);
        BARX;
        MMG(aA, bA, 2);
        if (s2) VMW(2);
        BARX;
    }
    MMG(aB, bB, 0);
    MMG(aB, bB, 2);
#undef RD_A
#undef RD_B
#undef MMG
#undef STAGE_A
#undef STAGE_B
    for (int i = 0; i < 4; i++) {
        int trow = t0 + wm * 64 + i * 16 + rg * 4;
        for (int j = 0; j < 4; j++) {
            int col = n0 + wn * 64 + j * 16 + rl;
            for (int r = 0; r < 4; r++)
                Cf[(size_t)(trow + r) * 2048 + col] = acc[i][j][r];
        }
    }
}

// ---------------- out-proj partial add ----------------
__global__ void k_oadd(const float* __restrict__ p, float* __restrict__ out) {
    int i = blockIdx.x * 256 + threadIdx.x;
    f32x4 a = *(const f32x4*)(p + (size_t)i * 4);
    f32x4 b = *(const f32x4*)(p + (size_t)4194304 + i * 4);
    for (int j = 0; j < 4; j++) a[j] += b[j];
    *(f32x4*)(out + (size_t)i * 4) = a;
}

// ---------------- differential flash attention (swapped-QK, 2 q-tiles/wave) -
// Balanced CU pairing: blocks b and b+256 co-reside; qs mapping makes every
// pair sum to 34 block-iters, and they share g=b&31 (K/V in L2).
// 1 barrier/tile; 2 q-tiles/wave. (unchanged from R18, which passed)
__global__ __launch_bounds__(256, 2)
void k_flash(const u16* __restrict__ qb_, const u16* __restrict__ kb,
             const u16* __restrict__ vt, u16* __restrict__ Ob) {
    __shared__ u16 Vt[2][128 * 64];
    __shared__ u16 Pb[4][32 * 64];
    int b = blockIdx.x;
    int qs = (b < 256) ? (15 - (b >> 5)) : ((b - 256) >> 5);
    int g = b & 31;               // same-g blocks share XCD (stride 32 ≡ 0 mod 8)
    int h = g >> 1;
    int tid = threadIdx.x, lane = tid & 63, wid = tid >> 6;
    int q0w = qs * 128 + wid * 32;    // wave owns q rows [q0w, q0w+32)
    int rl = lane & 15, rg = lane >> 4;
    int rl7s = (rl & 7) << 4;     // bank swizzle
    // Q fragments (operand B of swapped QK), 2 q-halves
    s16x8 aQ[2][2];
    for (int mf = 0; mf < 2; mf++) {
        const u16* qbase = qb_ + ((size_t)(g * 2048 + q0w + mf * 16 + rl)) * 64 + rg * 8;
        aQ[mf][0] = *(const s16x8*)qbase;
        aQ[mf][1] = *(const s16x8*)(qbase + 32);
    }
    // staging / fragment address bases
    int srow = tid >> 3;          // 0..31
    int scol = (tid & 7) * 8;     // 0..56
    const u16* vbase = vt + ((size_t)(h * 128 + srow)) * 2048 + scol;
    const u16* kbase = kb + ((size_t)(g * 2048 + rl)) * 64 + rg * 8;
    // prologue: tile 0 into regs
    s16x8 vv[4], bK[4][2];
    for (int p = 0; p < 4; p++) vv[p] = *(const s16x8*)(vbase + (size_t)p * 32 * 2048);
    for (int nf = 0; nf < 4; nf++)
        for (int ks = 0; ks < 2; ks++)
            bK[nf][ks] = *(const s16x8*)(kbase + (size_t)nf * 16 * 64 + ks * 32);
    f32x4 Oa[2][8] = {};
    float mrow[2] = {-3e38f, -3e38f}, lrow[2] = {0.f, 0.f};
    char* pbw = (char*)&Pb[wid][0];
    int ntiles = 2 * qs + 2;
    for (int it = 0; it < ntiles; it++) {
        int kv0 = it * 64;
        char* Vb = (char*)&Vt[it & 1][0];
        // write staged V (swizzled) — block-cooperative, unconditional
        for (int p = 0; p < 4; p++) {
            int row = srow + p * 32;
            *(s16x8*)(Vb + ((row * 128 + scol * 2) ^ ((row & 7) << 4))) = vv[p];
        }
        bool more = (it + 1 < ntiles);
        if (more)
            for (int p = 0; p < 4; p++)
                vv[p] = *(const s16x8*)(vbase + (size_t)p * 32 * 2048 + kv0 + 64);
        __syncthreads();
        bool active = (kv0 <= q0w + 31);           // wave-uniform
        bool nextact = more && (kv0 + 64 <= q0w + 31);
        if (active) {
            // S^T = K.Q^T : St[mf][nf][r] = S[kv0+nf*16+rg*4+r][q0w+mf*16+rl]
            f32x4 St[2][4];
            for (int mf = 0; mf < 2; mf++)
                for (int nf = 0; nf < 4; nf++) {
                    f32x4 s = {};
                    s = __builtin_amdgcn_mfma_f32_16x16x32_bf16(bK[nf][0], aQ[mf][0], s, 0, 0, 0);
                    s = __builtin_amdgcn_mfma_f32_16x16x32_bf16(bK[nf][1], aQ[mf][1], s, 0, 0, 0);
                    St[mf][nf] = s;
                }
            if (nextact)
                for (int nf = 0; nf < 4; nf++)
                    for (int ks = 0; ks < 2; ks++)
                        bK[nf][ks] = *(const s16x8*)(kbase + (size_t)(kv0 + 64 + nf * 16) * 64 + ks * 32);
            if (kv0 + 63 > q0w) {     // diagonal region: per-element mask
                for (int mf = 0; mf < 2; mf++) {
                    int q = q0w + mf * 16 + rl;
                    for (int nf = 0; nf < 4; nf++)
                        for (int r = 0; r < 4; r++)
                            if (kv0 + nf * 16 + rg * 4 + r > q) St[mf][nf][r] = NEGV;
                }
            }
            // two independent softmax chains (ILP)
            float pmax[2];
            for (int mf = 0; mf < 2; mf++) {
                float m0 = fmaxf(fmaxf(St[mf][0][0], St[mf][0][1]), fmaxf(St[mf][0][2], St[mf][0][3]));
                float m1 = fmaxf(fmaxf(St[mf][1][0], St[mf][1][1]), fmaxf(St[mf][1][2], St[mf][1][3]));
                float m2 = fmaxf(fmaxf(St[mf][2][0], St[mf][2][1]), fmaxf(St[mf][2][2], St[mf][2][3]));
                float m3 = fmaxf(fmaxf(St[mf][3][0], St[mf][3][1]), fmaxf(St[mf][3][2], St[mf][3][3]));
                float px = fmaxf(fmaxf(m0, m1), fmaxf(m2, m3));
                px = fmaxf(px, __shfl_xor(px, 16));
                px = fmaxf(px, __shfl_xor(px, 32));
                pmax[mf] = px;
            }
            // defer-max (T13) per half
            for (int mf = 0; mf < 2; mf++) {
                if (__any(pmax[mf] > mrow[mf] + 8.f)) {
                    float nm = fmaxf(mrow[mf], pmax[mf]);
                    float sc = __expf(mrow[mf] - nm);
                    mrow[mf] = nm;
                    lrow[mf] *= sc;
                    int sci = __builtin_bit_cast(int, sc);
                    for (int r = 0; r < 4; r++) {
                        float sr = __builtin_bit_cast(float,
                            __builtin_amdgcn_ds_bpermute((rg * 20 + r) * 4, sci));
                        for (int nf = 0; nf < 8; nf++) Oa[mf][nf][r] *= sr;
                    }
                }
            }
            // P = exp(S - mrow); row sums
            for (int mf = 0; mf < 2; mf++) {
                for (int nf = 0; nf < 4; nf++)
                    for (int r = 0; r < 4; r++)
                        St[mf][nf][r] = __expf(St[mf][nf][r] - mrow[mf]);
                float s0 = (St[mf][0][0] + St[mf][0][1]) + (St[mf][0][2] + St[mf][0][3]);
                float s1 = (St[mf][1][0] + St[mf][1][1]) + (St[mf][1][2] + St[mf][1][3]);
                float s2 = (St[mf][2][0] + St[mf][2][1]) + (St[mf][2][2] + St[mf][2][3]);
                float s3 = (St[mf][3][0] + St[mf][3][1]) + (St[mf][3][2] + St[mf][3][3]);
                float rs = (s0 + s1) + (s2 + s3);
                rs += __shfl_xor(rs, 16);
                rs += __shfl_xor(rs, 32);
                lrow[mf] += rs;
            }
            // pack P^T -> row-q LDS (per-wave, swizzled); rows mf*16+rl
            for (int mf = 0; mf < 2; mf++) {
                char* pm = pbw + (mf * 16 + rl) * 128;
                for (int nf = 0; nf < 4; nf++) {
                    unsigned int w0 = cvt_pk_bf16(St[mf][nf][0], St[mf][nf][1]);
                    unsigned int w1 = cvt_pk_bf16(St[mf][nf][2], St[mf][nf][3]);
                    u32x2 wp = {w0, w1};
                    *(u32x2*)(pm + ((nf * 32 + rg * 8) ^ rl7s)) = wp;
                }
            }
            s16x8 aP[2][2];
            for (int mf = 0; mf < 2; mf++) {
                char* pm = pbw + (mf * 16 + rl) * 128;
                for (int ks = 0; ks < 2; ks++)
                    aP[mf][ks] = *(const s16x8*)(pm + ((ks * 64 + rg * 16) ^ rl7s));
            }
            // PV: each bV read shared by both q-halves
            for (int ks = 0; ks < 2; ks++)
                for (int nf = 0; nf < 8; nf++) {
                    int row = nf * 16 + rl;
                    s16x8 bV = *(const s16x8*)(Vb + ((row * 128 + ks * 64 + rg * 16) ^ ((row & 7) << 4)));
                    Oa[0][nf] = __builtin_amdgcn_mfma_f32_16x16x32_bf16(aP[0][ks], bV, Oa[0][nf], 0, 0, 0);
                    Oa[1][nf] = __builtin_amdgcn_mfma_f32_16x16x32_bf16(aP[1][ks], bV, Oa[1][nf], 0, 0, 0);
                }
        }
        // no trailing barrier: next iter's mid-barrier orders reuse of Vt[it&1]
    }
    // epilogue: broadcast 1/l per half, write bf16
    for (int mf = 0; mf < 2; mf++) {
        float inv = 1.f / lrow[mf];
        int invi = __builtin_bit_cast(int, inv);
        for (int r = 0; r < 4; r++) {
            float ir = __builtin_bit_cast(float,
                __builtin_amdgcn_ds_bpermute((rg * 20 + r) * 4, invi));
            int t = q0w + mf * 16 + rg * 4 + r;
            for (int nf = 0; nf < 8; nf++)
                Ob[((size_t)(g * 2048 + t)) * 128 + nf * 16 + rl] = f2bf(Oa[mf][nf][r] * ir);
        }
    }
}

// ---------------- combine O0 - lam*O1, RMSNorm, -> bf16 (t, e) ----------------
__global__ __launch_bounds__(256)
void k_combine(const u16* __restrict__ O, const float* __restrict__ lamp,
               const float* __restrict__ subw, u16* __restrict__ Ab) {
    int gw = blockIdx.x * 4 + (threadIdx.x >> 6);  // 0..32767
    int lane = threadIdx.x & 63;
    int h = gw >> 11;
    int t = gw & 2047;
    float lam = *lamp;
    const u16* o0 = O + ((size_t)((2 * h) * 2048 + t)) * 128 + lane * 2;
    const u16* o1 = O + ((size_t)((2 * h + 1) * 2048 + t)) * 128 + lane * 2;
    unsigned int p0 = *(const unsigned int*)o0;
    unsigned int p1 = *(const unsigned int*)o1;
    float a0 = bf2f(p0 & 0xffffu) - lam * bf2f(p1 & 0xffffu);
    float a1 = bf2f(p0 >> 16) - lam * bf2f(p1 >> 16);
    float ss = a0 * a0 + a1 * a1;
    for (int m = 1; m < 64; m <<= 1) ss += __shfl_xor(ss, m);
    float inv = rsqrtf(ss * (1.f / 128.f) + 1e-5f) * (1.f - LAMBDA_INIT);
    a0 *= inv * subw[lane * 2];
    a1 *= inv * subw[lane * 2 + 1];
    unsigned int pk = (unsigned int)f2bf(a0) | ((unsigned int)f2bf(a1) << 16);
    *(unsigned int*)(Ab + (size_t)t * 2048 + h * 128 + lane * 2) = pk;
}

extern "C" void kernel_launch(void* const* d_in, const int* in_sizes, int n_in,
                              void* d_out, int out_size, void* d_ws, size_t ws_size,
                              hipStream_t stream) {
    const float* x    = (const float*)d_in[0];
    const float* Wq   = (const float*)d_in[2];
    const float* Wk   = (const float*)d_in[3];
    const float* Wv   = (const float*)d_in[4];
    const float* Wo   = (const float*)d_in[5];
    const float* lq1  = (const float*)d_in[6];
    const float* lk1  = (const float*)d_in[7];
    const float* lq2  = (const float*)d_in[8];
    const float* lk2  = (const float*)d_in[9];
    const float* subw = (const float*)d_in[10];
    float* out = (float*)d_out;

    char* ws = (char*)d_ws;
    size_t off = 0;
    auto alloc = [&](size_t sz) -> char* {
        char* p = ws + off;
        off = (off + sz + 255) & ~(size_t)255;
        return p;
    };
    float* lam  = (float*)alloc(4);
    float* cost = (float*)alloc((size_t)T_SEQ * 32 * 4);
    float* sint = (float*)alloc((size_t)T_SEQ * 32 * 4);
    u16* xbf   = (u16*)alloc((size_t)T_SEQ * EMB * 2);
    u16* wqkvt = (u16*)alloc((size_t)3 * EMB * EMB * 2);   // [WqT;WkT;WvT] 6144x2048
    u16* wot   = (u16*)alloc((size_t)EMB * EMB * 2);
    u16* qkbuf = (u16*)alloc((size_t)2 * G32 * T_SEQ * DH * 2);  // qbf | kbf
    u16* vtb   = (u16*)alloc((size_t)NHEAD * DV * T_SEQ * 2);
    u16* Obuf  = (u16*)alloc((size_t)G32 * T_SEQ * DV * 2);
    u16* Abf   = (u16*)alloc((size_t)T_SEQ * EMB * 2);
    float* parts = (float*)alloc((size_t)2 * EMB * EMB * 4);     // split-K partials
    u16* qbf = qkbuf;
    u16* kbf = qkbuf + (size_t)G32 * T_SEQ * DH;
    u16* vbf = (u16*)parts;  // alias: V (t,e) bf16, consumed before out-proj partials

    k_lambda<<<1, 64, 0, stream>>>(lq1, lk1, lq2, lk2, lam);
    k_ropetab<<<256, 256, 0, stream>>>(cost, sint);
    k_cvt_x<<<4096, 256, 0, stream>>>(x, xbf);
    k_transpose_cvt<<<dim3(64, 64, 4), 256, 0, stream>>>(Wq, Wk, Wv, Wo, wqkvt, wot);
    // fused Q|K|V projection (N=6144), pipelined 256x256 kernel, XCD-patch map
    k_gemm8<<<192, 512, 0, stream>>>(xbf, wqkvt, qkbuf, vbf, cost, sint);
    k_transpose_bf<<<dim3(32, 32), 256, 0, stream>>>(vbf, vtb);
    k_flash<<<512, 256, 0, stream>>>(qbf, kbf, vtb, Obuf);
    k_combine<<<8192, 256, 0, stream>>>(Obuf, lam, subw, Abf);
    // out projection, split-K=2, pipelined 128x128 kernel
    k_gemm0<<<dim3(16, 16, 2), 256, 0, stream>>>(Abf, wot, parts);
    k_oadd<<<4096, 256, 0, stream>>>(parts, out);
}

// Round 21
// 190.036 us; speedup vs baseline: 1.1058x; 1.0001x over previous
//
#include <hip/hip_runtime.h>

typedef __attribute__((ext_vector_type(4))) float f32x4;
typedef __attribute__((ext_vector_type(8))) short s16x8;
typedef __attribute__((ext_vector_type(4))) short s16x4;
typedef __attribute__((ext_vector_type(2))) unsigned int u32x2;
typedef unsigned short u16;

#define T_SEQ 2048
#define EMB   2048
#define NHEAD 16
#define G32   32
#define DH    64
#define DV    128
#define NEGV  (-1e9f)
// LAMBDA_INIT = 0.8 - 0.6*exp(-0.3*12)
#define LAMBDA_INIT 0.7836057665316245f
#define SCALING 0.125f

__device__ __forceinline__ u16 f2bf(float f) {
    unsigned int u = __builtin_bit_cast(unsigned int, f);
    unsigned int r = (u + 0x7fffu + ((u >> 16) & 1u)) >> 16;
    return (u16)r;
}
__device__ __forceinline__ float bf2f(unsigned int u) {
    return __builtin_bit_cast(float, u << 16);
}
__device__ __forceinline__ unsigned int cvt_pk_bf16(float lo, float hi) {
    unsigned int r;
    asm("v_cvt_pk_bf16_f32 %0, %1, %2" : "=v"(r) : "v"(lo), "v"(hi));
    return r;
}
__device__ __forceinline__ void load16(const u16* g, u16* l) {
    __builtin_amdgcn_global_load_lds(
        (const __attribute__((address_space(1))) unsigned int*)g,
        (__attribute__((address_space(3))) unsigned int*)l, 16, 0, 0);
}

#define BARX asm volatile("s_barrier" ::: "memory")
#define VMW(n) asm volatile("s_waitcnt vmcnt(" #n ")" ::: "memory")

// ---------------- lambda scalar ----------------
__global__ void k_lambda(const float* lq1, const float* lk1,
                         const float* lq2, const float* lk2, float* lam) {
    int l = threadIdx.x;  // 64
    float a = lq1[l] * lk1[l];
    float b = lq2[l] * lk2[l];
    for (int m = 32; m; m >>= 1) { a += __shfl_xor(a, m); b += __shfl_xor(b, m); }
    if (l == 0) *lam = __expf(a) - __expf(b) + LAMBDA_INIT;
}

// ---------------- rope tables (2048 x 32) ----------------
__global__ void k_ropetab(float* cost, float* sint) {
    int i = blockIdx.x * 256 + threadIdx.x;  // 65536
    int j = i & 31, t = i >> 5;
    double invf = exp(-(double)j * (9.210340371976184 / 32.0));  // 10000^(-j/32)
    double fr = (double)t * invf;
    cost[i] = (float)cos(fr);
    sint[i] = (float)sin(fr);
}

// ---------------- x fp32 -> bf16 ----------------
__global__ void k_cvt_x(const float* __restrict__ in, u16* __restrict__ out) {
    int i = blockIdx.x * 256 + threadIdx.x;  // one per 4 elems
    f32x4 v = *(const f32x4*)(in + (size_t)i * 4);
    s16x4 o;
    for (int j = 0; j < 4; j++) o[j] = (short)f2bf(v[j]);
    *(s16x4*)(out + (size_t)i * 4) = o;
}

// ---------------- 4x 2048x2048 fp32 -> transposed bf16 (one dispatch) -------
__global__ __launch_bounds__(256)
void k_transpose_cvt(const float* __restrict__ s0, const float* __restrict__ s1,
                     const float* __restrict__ s2, const float* __restrict__ s3,
                     u16* __restrict__ dqkv, u16* __restrict__ dwo) {
    __shared__ float tile[32][33];
    int z = blockIdx.z;
    const float* in = (z == 0) ? s0 : (z == 1) ? s1 : (z == 2) ? s2 : s3;
    u16* out = (z < 3) ? dqkv + (size_t)z * EMB * EMB : dwo;
    int lc = threadIdx.x & 31;
    int lr0 = (threadIdx.x >> 5) * 4;
    int col = blockIdx.x * 32 + lc;
    int row0 = blockIdx.y * 32 + lr0;
    for (int r = 0; r < 4; r++)
        tile[lr0 + r][lc] = in[(size_t)(row0 + r) * 2048 + col];
    __syncthreads();
    int ncol = blockIdx.y * 32 + lc;
    int nrow0 = blockIdx.x * 32 + lr0;
    for (int r = 0; r < 4; r++)
        out[(size_t)(nrow0 + r) * 2048 + ncol] = f2bf(tile[lc][lr0 + r]);
}

// ---------------- 2048x2048 bf16 -> transposed bf16 (V) ----------------------
__global__ __launch_bounds__(256)
void k_transpose_bf(const u16* __restrict__ in, u16* __restrict__ out) {
    __shared__ u16 tl[64][72];
    int tid = threadIdx.x;
    int lr = tid >> 3;            // 0..31
    int lc8 = (tid & 7) * 8;      // 0..56
    int row0 = blockIdx.y * 64, col0 = blockIdx.x * 64;
    for (int p = 0; p < 2; p++) {
        int r = lr + p * 32;
        *(s16x8*)&tl[r][lc8] = *(const s16x8*)(in + (size_t)(row0 + r) * 2048 + col0 + lc8);
    }
    __syncthreads();
    for (int p = 0; p < 2; p++) {
        int c = lr + p * 32;      // output row = original col
        s16x8 v;
        for (int j = 0; j < 8; j++) v[j] = tl[lc8 + j][c];
        *(s16x8*)(out + (size_t)(col0 + c) * 2048 + row0 + lc8) = v;
    }
}

// ---------------- pipelined 256x256 GEMM, fused QKV epilogue -----------------
// XCD-patch block remap (R20, passed): XCD owns a 4bm x 6bn patch.
__global__ __launch_bounds__(512, 2)
void k_gemm8(const u16* __restrict__ A, const u16* __restrict__ Bt,
             u16* __restrict__ Cqk, u16* __restrict__ Cv,
             const float* __restrict__ costab, const float* __restrict__ sintab) {
    __shared__ u16 sm[32768];   // 64 KB: buf{0,1} x { A 256x32 | B 256x32 }
    int tid = threadIdx.x;
    int w = tid >> 6, l = tid & 63;
    int wm = w >> 2, wn = w & 3;
    int rl = l & 15, rg = l >> 4;
    int xcd = blockIdx.x & 7, ii = blockIdx.x >> 3;
    int bm = (xcd & 1) * 4 + (ii & 3);
    int bn = (xcd >> 1) * 6 + (ii >> 2);
    int t0 = bm * 256, n0 = bn * 256;
    int colA = (rg * 8) ^ (((rl >> 1) & 3) << 3);
    int aBase = wm * 4096 + rl * 32 + colA;
    int bBase = 8192 + (wn >> 1) * 4096 + (wn & 1) * 2048 + rl * 32 + colA;
    int srow = w * 16 + (l >> 2);                     // 0..127 within half
    int cxor = (((l & 3) ^ ((l >> 3) & 3)) << 3);     // source col elems
    int dstoff = w * 512 + l * 8;                     // elems within half
    const u16* Ag = A + (size_t)t0 * 2048 + cxor;
    const u16* Bg = Bt + (size_t)n0 * 2048 + cxor;

#define RD_A(arr, co) { _Pragma("unroll") for (int m_ = 0; m_ < 8; m_++) \
    arr[m_] = *(const s16x8*)&sm[(co) + aBase + m_ * 512]; }
#define RD_B(arr, co) { _Pragma("unroll") for (int n_ = 0; n_ < 4; n_++) \
    arr[n_] = *(const s16x8*)&sm[(co) + bBase + n_ * 512]; }
#define MMG(aa, bb, nlo) { __builtin_amdgcn_s_setprio(1); \
    _Pragma("unroll") for (int q_ = 0; q_ < 8; q_++) { \
      acc[q_][nlo]     = __builtin_amdgcn_mfma_f32_16x16x32_bf16(aa[q_], bb[nlo],     acc[q_][nlo],     0, 0, 0); \
      acc[q_][nlo + 1] = __builtin_amdgcn_mfma_f32_16x16x32_bf16(aa[q_], bb[nlo + 1], acc[q_][nlo + 1], 0, 0, 0); } \
    __builtin_amdgcn_s_setprio(0); }
#define STAGE_A(tile) { int nb_ = ((tile) & 1) * 16384; \
    const u16* s_ = Ag + (size_t)srow * 2048 + (tile) * 32; \
    load16(s_, sm + nb_ + dstoff); \
    load16(s_ + (size_t)128 * 2048, sm + nb_ + 4096 + dstoff); }
#define STAGE_B(tile) { int nb_ = ((tile) & 1) * 16384 + 8192; \
    const u16* s_ = Bg + (size_t)srow * 2048 + (tile) * 32; \
    load16(s_, sm + nb_ + dstoff); \
    load16(s_ + (size_t)128 * 2048, sm + nb_ + 4096 + dstoff); }

    f32x4 acc[8][4] = {};
    s16x8 aA[8], aB[8], bA[4], bB[4];
    STAGE_A(0); STAGE_B(0);
    VMW(2); BARX;
    for (int i = 0; i < 32; i++) {
        int e = 2 * i;
        bool s2 = i < 31;
        RD_A(aA, 0);
        STAGE_A(e + 1);
        BARX;
        if (i) MMG(aB, bB, 0);
        VMW(2); BARX;
        RD_B(bA, 0);
        STAGE_B(e + 1);
        BARX;
        if (i) MMG(aB, bB, 2);
        VMW(2); BARX;
        RD_A(aB, 16384);
        if (s2) STAGE_A(e + 2);
        BARX;
        MMG(aA, bA, 0);
        if (s2) { VMW(2); } else { VMW(0); }
        BARX;
        RD_B(bB, 16384);
        if (s2) STAGE_B(e + 2);
        BARX;
        MMG(aA, bA, 2);
        if (s2) VMW(2);
        BARX;
    }
    MMG(aB, bB, 0);
    MMG(aB, bB, 2);
#undef RD_A
#undef RD_B
#undef MMG
#undef STAGE_A
#undef STAGE_B
    int nbase = n0 + wn * 64;          // wave's 64 cols = one sub-head
    if (nbase >= 4096) {
        int col = nbase - 4096;
        for (int m = 0; m < 8; m++) {
            int trow = t0 + wm * 128 + m * 16 + rg * 4;
            for (int n = 0; n < 4; n++)
                for (int r = 0; r < 4; r++)
                    Cv[(size_t)(trow + r) * 2048 + col + n * 16 + rl] = f2bf(acc[m][n][r]);
        }
    } else {
        const bool isQ = nbase < 2048;
        u16* dst = isQ ? Cqk : Cqk + (size_t)G32 * 2048 * 64;
        int g = (isQ ? nbase : nbase - 2048) >> 6;
        float fs = isQ ? SCALING : 1.0f;
        for (int m = 0; m < 8; m++) {
            int trow = t0 + wm * 128 + m * 16 + rg * 4;
            for (int n = 0; n < 4; n++) {
                int d = n * 16 + rl;           // 0..63
                int np = n ^ 2;                // paired fragment (d +/- 32)
                float sgn = (n < 2) ? -1.f : 1.f;
                for (int r = 0; r < 4; r++) {
                    int t = trow + r;
                    float c = costab[t * 32 + (d & 31)];
                    float s = sintab[t * 32 + (d & 31)];
                    float v = (acc[m][n][r] * c + sgn * acc[m][np][r] * s) * fs;
                    dst[((size_t)g * 2048 + t) * 64 + d] = f2bf(v);
                }
            }
        }
    }
}

// ---------------- pipelined 128x128 GEMM, split-K=2 fp32 partials (out-proj) -
// (unchanged from R18, which passed)
__global__ __launch_bounds__(256, 2)
void k_gemm0(const u16* __restrict__ A, const u16* __restrict__ Bt,
             float* __restrict__ Cf) {
    __shared__ u16 sm[16384];   // 32 KB: buf{0,1} x { A 128x32 | B 128x32 }
    int tid = threadIdx.x;
    int w = tid >> 6, l = tid & 63;
    int wm = w >> 1, wn = w & 1;
    int rl = l & 15, rg = l >> 4;
    int t0 = blockIdx.y * 128, n0 = blockIdx.x * 128;
    int kbase = blockIdx.z * 1024;     // 32 K-tiles of 32
    Cf += (size_t)blockIdx.z * 2048 * 2048;
    int colA = (rg * 8) ^ (((rl >> 1) & 3) << 3);
    int aBase = wm * 2048 + rl * 32 + colA;
    int bBase = 4096 + wn * 2048 + rl * 32 + colA;
    int srow = tid >> 2;                               // 0..63
    int cxor = (((tid & 3) ^ ((tid >> 3) & 3)) << 3);  // source col pre-swizzle
    int dstoff = tid * 8;                              // elems
    const u16* Ag = A + (size_t)t0 * 2048 + kbase + cxor;
    const u16* Bg = Bt + (size_t)n0 * 2048 + kbase + cxor;

#define RD_A(arr, co) { _Pragma("unroll") for (int m_ = 0; m_ < 4; m_++) \
    arr[m_] = *(const s16x8*)&sm[(co) + aBase + m_ * 512]; }
#define RD_B(arr, co) { _Pragma("unroll") for (int n_ = 0; n_ < 4; n_++) \
    arr[n_] = *(const s16x8*)&sm[(co) + bBase + n_ * 512]; }
#define MMG(aa, bb, nlo) { __builtin_amdgcn_s_setprio(1); \
    _Pragma("unroll") for (int q_ = 0; q_ < 4; q_++) { \
      acc[q_][nlo]     = __builtin_amdgcn_mfma_f32_16x16x32_bf16(aa[q_], bb[nlo],     acc[q_][nlo],     0, 0, 0); \
      acc[q_][nlo + 1] = __builtin_amdgcn_mfma_f32_16x16x32_bf16(aa[q_], bb[nlo + 1], acc[q_][nlo + 1], 0, 0, 0); } \
    __builtin_amdgcn_s_setprio(0); }
#define STAGE_A(tile) { int nb_ = ((tile) & 1) * 8192; \
    const u16* s_ = Ag + (size_t)srow * 2048 + (tile) * 32; \
    load16(s_, sm + nb_ + dstoff); \
    load16(s_ + (size_t)64 * 2048, sm + nb_ + 2048 + dstoff); }
#define STAGE_B(tile) { int nb_ = ((tile) & 1) * 8192 + 4096; \
    const u16* s_ = Bg + (size_t)srow * 2048 + (tile) * 32; \
    load16(s_, sm + nb_ + dstoff); \
    load16(s_ + (size_t)64 * 2048, sm + nb_ + 2048 + dstoff); }

    f32x4 acc[4][4] = {};
    s16x8 aA[4], aB[4], bA[4], bB[4];
    STAGE_A(0); STAGE_B(0);
    VMW(2); BARX;
    for (int i = 0; i < 16; i++) {
        int e = 2 * i;
        bool s2 = i < 15;
        RD_A(aA, 0);
        STAGE_A(e + 1);
        BARX;
        if (i) MMG(aB, bB, 0);
        VMW(2); BARX;
        RD_B(bA, 0);
        STAGE_B(e + 1);
        BARX;
        if (i) MMG(aB, bB, 2);
        VMW(2); BARX;
        RD_A(aB, 8192);
        if (s2) STAGE_A(e + 2);
        BARX;
        MMG(aA, bA, 0);
        if (s2) { VMW(2); } else { VMW(0); }
        BARX;
        RD_B(bB, 8192);
        if (s2) STAGE_B(e + 2);
        BARX;
        MMG(aA, bA, 2);
        if (s2) VMW(2);
        BARX;
    }
    MMG(aB, bB, 0);
    MMG(aB, bB, 2);
#undef RD_A
#undef RD_B
#undef MMG
#undef STAGE_A
#undef STAGE_B
    for (int i = 0; i < 4; i++) {
        int trow = t0 + wm * 64 + i * 16 + rg * 4;
        for (int j = 0; j < 4; j++) {
            int col = n0 + wn * 64 + j * 16 + rl;
            for (int r = 0; r < 4; r++)
                Cf[(size_t)(trow + r) * 2048 + col] = acc[i][j][r];
        }
    }
}

// ---------------- out-proj partial add ----------------
__global__ void k_oadd(const float* __restrict__ p, float* __restrict__ out) {
    int i = blockIdx.x * 256 + threadIdx.x;
    f32x4 a = *(const f32x4*)(p + (size_t)i * 4);
    f32x4 b = *(const f32x4*)(p + (size_t)4194304 + i * 4);
    for (int j = 0; j < 4; j++) a[j] += b[j];
    *(f32x4*)(out + (size_t)i * 4) = a;
}

// ---------------- differential flash attention (swapped-QK, 2 q-tiles/wave) -
// R20 structure + T5: s_setprio(1) around QK and PV MFMA clusters (attn-proven
// lever, m191: helps when co-resident waves/blocks are at different phases —
// here heavy+light qs pairs per CU + wave-divergent active paths).
__global__ __launch_bounds__(256, 2)
void k_flash(const u16* __restrict__ qb_, const u16* __restrict__ kb,
             const u16* __restrict__ vt, u16* __restrict__ Ob) {
    __shared__ u16 Vt[2][128 * 64];
    __shared__ u16 Pb[4][32 * 64];
    int b = blockIdx.x;
    int qs = (b < 256) ? (15 - (b >> 5)) : ((b - 256) >> 5);
    int g = b & 31;               // same-g blocks share XCD (stride 32 ≡ 0 mod 8)
    int h = g >> 1;
    int tid = threadIdx.x, lane = tid & 63, wid = tid >> 6;
    int q0w = qs * 128 + wid * 32;    // wave owns q rows [q0w, q0w+32)
    int rl = lane & 15, rg = lane >> 4;
    int rl7s = (rl & 7) << 4;     // bank swizzle
    // Q fragments (operand B of swapped QK), 2 q-halves
    s16x8 aQ[2][2];
    for (int mf = 0; mf < 2; mf++) {
        const u16* qbase = qb_ + ((size_t)(g * 2048 + q0w + mf * 16 + rl)) * 64 + rg * 8;
        aQ[mf][0] = *(const s16x8*)qbase;
        aQ[mf][1] = *(const s16x8*)(qbase + 32);
    }
    // staging / fragment address bases
    int srow = tid >> 3;          // 0..31
    int scol = (tid & 7) * 8;     // 0..56
    const u16* vbase = vt + ((size_t)(h * 128 + srow)) * 2048 + scol;
    const u16* kbase = kb + ((size_t)(g * 2048 + rl)) * 64 + rg * 8;
    // prologue: tile 0 into regs
    s16x8 vv[4], bK[4][2];
    for (int p = 0; p < 4; p++) vv[p] = *(const s16x8*)(vbase + (size_t)p * 32 * 2048);
    for (int nf = 0; nf < 4; nf++)
        for (int ks = 0; ks < 2; ks++)
            bK[nf][ks] = *(const s16x8*)(kbase + (size_t)nf * 16 * 64 + ks * 32);
    f32x4 Oa[2][8] = {};
    float mrow[2] = {-3e38f, -3e38f}, lrow[2] = {0.f, 0.f};
    char* pbw = (char*)&Pb[wid][0];
    int ntiles = 2 * qs + 2;
    for (int it = 0; it < ntiles; it++) {
        int kv0 = it * 64;
        char* Vb = (char*)&Vt[it & 1][0];
        // write staged V (swizzled) — block-cooperative, unconditional
        for (int p = 0; p < 4; p++) {
            int row = srow + p * 32;
            *(s16x8*)(Vb + ((row * 128 + scol * 2) ^ ((row & 7) << 4))) = vv[p];
        }
        bool more = (it + 1 < ntiles);
        if (more)
            for (int p = 0; p < 4; p++)
                vv[p] = *(const s16x8*)(vbase + (size_t)p * 32 * 2048 + kv0 + 64);
        __syncthreads();
        bool active = (kv0 <= q0w + 31);           // wave-uniform
        bool nextact = more && (kv0 + 64 <= q0w + 31);
        if (active) {
            // S^T = K.Q^T : St[mf][nf][r] = S[kv0+nf*16+rg*4+r][q0w+mf*16+rl]
            f32x4 St[2][4];
            __builtin_amdgcn_s_setprio(1);
            for (int mf = 0; mf < 2; mf++)
                for (int nf = 0; nf < 4; nf++) {
                    f32x4 s = {};
                    s = __builtin_amdgcn_mfma_f32_16x16x32_bf16(bK[nf][0], aQ[mf][0], s, 0, 0, 0);
                    s = __builtin_amdgcn_mfma_f32_16x16x32_bf16(bK[nf][1], aQ[mf][1], s, 0, 0, 0);
                    St[mf][nf] = s;
                }
            __builtin_amdgcn_s_setprio(0);
            if (nextact)
                for (int nf = 0; nf < 4; nf++)
                    for (int ks = 0; ks < 2; ks++)
                        bK[nf][ks] = *(const s16x8*)(kbase + (size_t)(kv0 + 64 + nf * 16) * 64 + ks * 32);
            if (kv0 + 63 > q0w) {     // diagonal region: per-element mask
                for (int mf = 0; mf < 2; mf++) {
                    int q = q0w + mf * 16 + rl;
                    for (int nf = 0; nf < 4; nf++)
                        for (int r = 0; r < 4; r++)
                            if (kv0 + nf * 16 + rg * 4 + r > q) St[mf][nf][r] = NEGV;
                }
            }
            // two independent softmax chains (ILP)
            float pmax[2];
            for (int mf = 0; mf < 2; mf++) {
                float m0 = fmaxf(fmaxf(St[mf][0][0], St[mf][0][1]), fmaxf(St[mf][0][2], St[mf][0][3]));
                float m1 = fmaxf(fmaxf(St[mf][1][0], St[mf][1][1]), fmaxf(St[mf][1][2], St[mf][1][3]));
                float m2 = fmaxf(fmaxf(St[mf][2][0], St[mf][2][1]), fmaxf(St[mf][2][2], St[mf][2][3]));
                float m3 = fmaxf(fmaxf(St[mf][3][0], St[mf][3][1]), fmaxf(St[mf][3][2], St[mf][3][3]));
                float px = fmaxf(fmaxf(m0, m1), fmaxf(m2, m3));
                px = fmaxf(px, __shfl_xor(px, 16));
                px = fmaxf(px, __shfl_xor(px, 32));
                pmax[mf] = px;
            }
            // defer-max (T13) per half
            for (int mf = 0; mf < 2; mf++) {
                if (__any(pmax[mf] > mrow[mf] + 8.f)) {
                    float nm = fmaxf(mrow[mf], pmax[mf]);
                    float sc = __expf(mrow[mf] - nm);
                    mrow[mf] = nm;
                    lrow[mf] *= sc;
                    int sci = __builtin_bit_cast(int, sc);
                    for (int r = 0; r < 4; r++) {
                        float sr = __builtin_bit_cast(float,
                            __builtin_amdgcn_ds_bpermute((rg * 20 + r) * 4, sci));
                        for (int nf = 0; nf < 8; nf++) Oa[mf][nf][r] *= sr;
                    }
                }
            }
            // P = exp(S - mrow); row sums
            for (int mf = 0; mf < 2; mf++) {
                for (int nf = 0; nf < 4; nf++)
                    for (int r = 0; r < 4; r++)
                        St[mf][nf][r] = __expf(St[mf][nf][r] - mrow[mf]);
                float s0 = (St[mf][0][0] + St[mf][0][1]) + (St[mf][0][2] + St[mf][0][3]);
                float s1 = (St[mf][1][0] + St[mf][1][1]) + (St[mf][1][2] + St[mf][1][3]);
                float s2 = (St[mf][2][0] + St[mf][2][1]) + (St[mf][2][2] + St[mf][2][3]);
                float s3 = (St[mf][3][0] + St[mf][3][1]) + (St[mf][3][2] + St[mf][3][3]);
                float rs = (s0 + s1) + (s2 + s3);
                rs += __shfl_xor(rs, 16);
                rs += __shfl_xor(rs, 32);
                lrow[mf] += rs;
            }
            // pack P^T -> row-q LDS (per-wave, swizzled); rows mf*16+rl
            for (int mf = 0; mf < 2; mf++) {
                char* pm = pbw + (mf * 16 + rl) * 128;
                for (int nf = 0; nf < 4; nf++) {
                    unsigned int w0 = cvt_pk_bf16(St[mf][nf][0], St[mf][nf][1]);
                    unsigned int w1 = cvt_pk_bf16(St[mf][nf][2], St[mf][nf][3]);
                    u32x2 wp = {w0, w1};
                    *(u32x2*)(pm + ((nf * 32 + rg * 8) ^ rl7s)) = wp;
                }
            }
            s16x8 aP[2][2];
            for (int mf = 0; mf < 2; mf++) {
                char* pm = pbw + (mf * 16 + rl) * 128;
                for (int ks = 0; ks < 2; ks++)
                    aP[mf][ks] = *(const s16x8*)(pm + ((ks * 64 + rg * 16) ^ rl7s));
            }
            // PV: each bV read shared by both q-halves
            __builtin_amdgcn_s_setprio(1);
            for (int ks = 0; ks < 2; ks++)
                for (int nf = 0; nf < 8; nf++) {
                    int row = nf * 16 + rl;
                    s16x8 bV = *(const s16x8*)(Vb + ((row * 128 + ks * 64 + rg * 16) ^ ((row & 7) << 4)));
                    Oa[0][nf] = __builtin_amdgcn_mfma_f32_16x16x32_bf16(aP[0][ks], bV, Oa[0][nf], 0, 0, 0);
                    Oa[1][nf] = __builtin_amdgcn_mfma_f32_16x16x32_bf16(aP[1][ks], bV, Oa[1][nf], 0, 0, 0);
                }
            __builtin_amdgcn_s_setprio(0);
        }
        // no trailing barrier: next iter's mid-barrier orders reuse of Vt[it&1]
    }
    // epilogue: broadcast 1/l per half, write bf16
    for (int mf = 0; mf < 2; mf++) {
        float inv = 1.f / lrow[mf];
        int invi = __builtin_bit_cast(int, inv);
        for (int r = 0; r < 4; r++) {
            float ir = __builtin_bit_cast(float,
                __builtin_amdgcn_ds_bpermute((rg * 20 + r) * 4, invi));
            int t = q0w + mf * 16 + rg * 4 + r;
            for (int nf = 0; nf < 8; nf++)
                Ob[((size_t)(g * 2048 + t)) * 128 + nf * 16 + rl] = f2bf(Oa[mf][nf][r] * ir);
        }
    }
}

// ---------------- combine O0 - lam*O1, RMSNorm, -> bf16 (t, e) ----------------
__global__ __launch_bounds__(256)
void k_combine(const u16* __restrict__ O, const float* __restrict__ lamp,
               const float* __restrict__ subw, u16* __restrict__ Ab) {
    int gw = blockIdx.x * 4 + (threadIdx.x >> 6);  // 0..32767
    int lane = threadIdx.x & 63;
    int h = gw >> 11;
    int t = gw & 2047;
    float lam = *lamp;
    const u16* o0 = O + ((size_t)((2 * h) * 2048 + t)) * 128 + lane * 2;
    const u16* o1 = O + ((size_t)((2 * h + 1) * 2048 + t)) * 128 + lane * 2;
    unsigned int p0 = *(const unsigned int*)o0;
    unsigned int p1 = *(const unsigned int*)o1;
    float a0 = bf2f(p0 & 0xffffu) - lam * bf2f(p1 & 0xffffu);
    float a1 = bf2f(p0 >> 16) - lam * bf2f(p1 >> 16);
    float ss = a0 * a0 + a1 * a1;
    for (int m = 1; m < 64; m <<= 1) ss += __shfl_xor(ss, m);
    float inv = rsqrtf(ss * (1.f / 128.f) + 1e-5f) * (1.f - LAMBDA_INIT);
    a0 *= inv * subw[lane * 2];
    a1 *= inv * subw[lane * 2 + 1];
    unsigned int pk = (unsigned int)f2bf(a0) | ((unsigned int)f2bf(a1) << 16);
    *(unsigned int*)(Ab + (size_t)t * 2048 + h * 128 + lane * 2) = pk;
}

extern "C" void kernel_launch(void* const* d_in, const int* in_sizes, int n_in,
                              void* d_out, int out_size, void* d_ws, size_t ws_size,
                              hipStream_t stream) {
    const float* x    = (const float*)d_in[0];
    const float* Wq   = (const float*)d_in[2];
    const float* Wk   = (const float*)d_in[3];
    const float* Wv   = (const float*)d_in[4];
    const float* Wo   = (const float*)d_in[5];
    const float* lq1  = (const float*)d_in[6];
    const float* lk1  = (const float*)d_in[7];
    const float* lq2  = (const float*)d_in[8];
    const float* lk2  = (const float*)d_in[9];
    const float* subw = (const float*)d_in[10];
    float* out = (float*)d_out;

    char* ws = (char*)d_ws;
    size_t off = 0;
    auto alloc = [&](size_t sz) -> char* {
        char* p = ws + off;
        off = (off + sz + 255) & ~(size_t)255;
        return p;
    };
    float* lam  = (float*)alloc(4);
    float* cost = (float*)alloc((size_t)T_SEQ * 32 * 4);
    float* sint = (float*)alloc((size_t)T_SEQ * 32 * 4);
    u16* xbf   = (u16*)alloc((size_t)T_SEQ * EMB * 2);
    u16* wqkvt = (u16*)alloc((size_t)3 * EMB * EMB * 2);   // [WqT;WkT;WvT] 6144x2048
    u16* wot   = (u16*)alloc((size_t)EMB * EMB * 2);
    u16* qkbuf = (u16*)alloc((size_t)2 * G32 * T_SEQ * DH * 2);  // qbf | kbf
    u16* vtb   = (u16*)alloc((size_t)NHEAD * DV * T_SEQ * 2);
    u16* Obuf  = (u16*)alloc((size_t)G32 * T_SEQ * DV * 2);
    u16* Abf   = (u16*)alloc((size_t)T_SEQ * EMB * 2);
    float* parts = (float*)alloc((size_t)2 * EMB * EMB * 4);     // split-K partials
    u16* qbf = qkbuf;
    u16* kbf = qkbuf + (size_t)G32 * T_SEQ * DH;
    u16* vbf = (u16*)parts;  // alias: V (t,e) bf16, consumed before out-proj partials

    k_lambda<<<1, 64, 0, stream>>>(lq1, lk1, lq2, lk2, lam);
    k_ropetab<<<256, 256, 0, stream>>>(cost, sint);
    k_cvt_x<<<4096, 256, 0, stream>>>(x, xbf);
    k_transpose_cvt<<<dim3(64, 64, 4), 256, 0, stream>>>(Wq, Wk, Wv, Wo, wqkvt, wot);
    // fused Q|K|V projection (N=6144), pipelined 256x256 kernel, XCD-patch map
    k_gemm8<<<192, 512, 0, stream>>>(xbf, wqkvt, qkbuf, vbf, cost, sint);
    k_transpose_bf<<<dim3(32, 32), 256, 0, stream>>>(vbf, vtb);
    k_flash<<<512, 256, 0, stream>>>(qbf, kbf, vtb, Obuf);
    k_combine<<<8192, 256, 0, stream>>>(Obuf, lam, subw, Abf);
    // out projection, split-K=2, pipelined 128x128 kernel
    k_gemm0<<<dim3(16, 16, 2), 256, 0, stream>>>(Abf, wot, parts);
    k_oadd<<<4096, 256, 0, stream>>>(parts, out);
}